// Round 6
// baseline (511.675 us; speedup 1.0000x reference)
//
#include <hip/hip_runtime.h>
#include <hip/hip_bf16.h>

#define D 256
#define BM 64
#define BN 512      // codes per tile (8 waves x 64)
#define NT 16       // 8192 / BN
#define NIT 128     // NT * 8 kc-chunks
#define CAP 64
#define MARGIN 1.2e-3f

typedef short bf16x8 __attribute__((ext_vector_type(8)));
typedef float f32x4 __attribute__((ext_vector_type(4)));

#define GLD16(gsrc, ldst) \
    __builtin_amdgcn_global_load_lds((const __attribute__((address_space(1))) void*)(gsrc), \
                                     (__attribute__((address_space(3))) void*)(ldst), 16, 0, 0)

__device__ inline unsigned short f2bf(float f) {
    __hip_bfloat16 h = __float2bfloat16(f);
    return *reinterpret_cast<unsigned short*>(&h);
}

// -------- kernel 0: fp32 -> bf16 convert (vectorized) --------
__global__ __launch_bounds__(256) void vq_tobf16(const float* __restrict__ in,
                                                 unsigned short* __restrict__ out, int n4) {
    int i = blockIdx.x * 256 + threadIdx.x;
    if (i >= n4) return;
    float4 v = ((const float4*)in)[i];
    ushort4 o;
    o.x = f2bf(v.x); o.y = f2bf(v.y); o.z = f2bf(v.z); o.w = f2bf(v.w);
    ((ushort4*)out)[i] = o;
}

// -------- kernel 1: sequential fp32 row sum-of-squares (XLA elemental order) ----
__global__ __launch_bounds__(256) void vq_rownorm(const float* __restrict__ x,
                                                  float* __restrict__ out,
                                                  int rows, float* loss_zero) {
#pragma clang fp contract(off)
    int r = blockIdx.x * blockDim.x + threadIdx.x;
    if (r == 0 && loss_zero) loss_zero[0] = 0.f;
    if (r >= rows) return;
    const float* p = x + (size_t)r * D;
    float s = 0.f;
    for (int d = 0; d < D; ++d) {
        float v = p[d];
        float pr = v * v;
        s = s + pr;
    }
    out[r] = s;
}

// -------- kernel 2: single-pass MFMA filter (async LDS B-staging) + rescore ----
__global__ __launch_bounds__(512, 2) void vq_argmin_mfma(
    const float* __restrict__ z, const float* __restrict__ emb,
    const unsigned short* __restrict__ zb, const unsigned short* __restrict__ eb,
    const float* __restrict__ znorm, const float* __restrict__ enorm,
    float* __restrict__ idxf, int K) {
#pragma clang fp contract(off)
    __shared__ unsigned short zsh[BM][264];   // 33,792 B
    __shared__ unsigned short esh[3][16384];  // 98,304 B: 3 bufs x 8 waves x 64 codes x 32 dims
    __shared__ unsigned rowmin[BM];
    __shared__ int cnt[BM];
    __shared__ int candT[CAP][BM];            // 16,384 B (slot-major)
    __shared__ unsigned sbits[BM];
    __shared__ int sidx[BM];
    __shared__ int ovList[16];
    __shared__ int ovCnt;

    const int tid = threadIdx.x;
    const int w = tid >> 6;        // wave 0..7
    const int l = tid & 63;
    const int q = l >> 4;          // 0..3
    const int lm = l & 15;
    const int rowBase = blockIdx.x * BM;

    if (tid < BM) {
        rowmin[tid] = 0x7f800000u; cnt[tid] = 0;
        sbits[tid] = 0xffffffffu;  sidx[tid] = 0x7fffffff;
    }
    if (tid == 0) ovCnt = 0;

    // stage z tile (bf16) into padded LDS (R4/R5-verified mapping)
    #pragma unroll
    for (int rc = 0; rc < 4; ++rc) {
        int idx8 = tid + rc * 512;
        int row = idx8 >> 5, c8 = idx8 & 31;
        uint4 v = *(const uint4*)(zb + (((size_t)(rowBase + row)) << 8) + c8 * 8);
        *(uint4*)&zsh[row][c8 * 8] = v;
    }

    f32x4 nz4[4];
    #pragma unroll
    for (int fr = 0; fr < 4; ++fr)
        nz4[fr] = *(const f32x4*)&znorm[rowBase + fr * 16 + q * 4];

    // async stage of this wave's 64-code kc-chunk: linear dest, linear source
    auto STAGE = [&](int buf, int it2) {
        const int tile2 = it2 >> 3, kc2 = it2 & 7;
        const int cb = tile2 * BN + w * 64;
        const char* ebase = (const char*)eb;
        #pragma unroll
        for (int rnd = 0; rnd < 4; ++rnd) {
            const char* src = ebase + (((size_t)(cb + rnd * 16 + (l >> 2))) << 9)
                            + kc2 * 64 + (l & 3) * 16;
            unsigned short* dst = &esh[buf][w * 2048 + rnd * 512];   // wave-uniform base
            GLD16(src, dst);
        }
    };

    __syncthreads();   // zsh + init visible; last block-wide barrier before main loop

    STAGE(0, 0);
    STAGE(1, 1);
    int cur = 0, nxt = 2;

    for (int tile = 0; tile < NT; ++tile) {
        const int codeBase = tile * BN + w * 64;
        // prefetch enorm for this tile's codes (latency hidden under kc loop)
        float ne[4];
        #pragma unroll
        for (int fc = 0; fc < 4; ++fc) ne[fc] = enorm[codeBase + fc * 16 + lm];

        f32x4 acc[4][4];
        #pragma unroll
        for (int a = 0; a < 4; ++a)
            #pragma unroll
            for (int b = 0; b < 4; ++b) acc[a][b] = (f32x4)0.f;

        #pragma unroll
        for (int kc = 0; kc < 8; ++kc) {
            const int it = tile * 8 + kc;
            if (it + 2 < NIT) STAGE(nxt, it + 2);
            // wave-local wait: everything older than the 2 in-flight stages retired
            if (it < NIT - 2)       asm volatile("s_waitcnt vmcnt(8)" ::: "memory");
            else if (it == NIT - 2) asm volatile("s_waitcnt vmcnt(4)" ::: "memory");
            else                    asm volatile("s_waitcnt vmcnt(0)" ::: "memory");
            __builtin_amdgcn_sched_barrier(0);

            bf16x8 af[4], bfr[4];
            #pragma unroll
            for (int fr = 0; fr < 4; ++fr)
                af[fr] = *(const bf16x8*)&zsh[fr * 16 + lm][kc * 32 + q * 8];
            #pragma unroll
            for (int fc = 0; fc < 4; ++fc)
                bfr[fc] = *(const bf16x8*)&esh[cur][w * 2048 + (fc * 16 + lm) * 32 + q * 8];

            __builtin_amdgcn_s_setprio(1);
            #pragma unroll
            for (int fr = 0; fr < 4; ++fr)
                #pragma unroll
                for (int fc = 0; fc < 4; ++fc)
                    acc[fr][fc] = __builtin_amdgcn_mfma_f32_16x16x32_bf16(af[fr], bfr[fc], acc[fr][fc], 0, 0, 0);
            __builtin_amdgcn_s_setprio(0);

            cur = (cur == 2) ? 0 : cur + 1;
            nxt = (nxt == 2) ? 0 : nxt + 1;
        }

        // ---- tile epilogue (no barriers): reg-min -> atomicMin -> collect ----
        f32x4 m4[4];
        #pragma unroll
        for (int fr = 0; fr < 4; ++fr) {
            #pragma unroll
            for (int e = 0; e < 4; ++e) {
                float m = 3.4e38f;
                #pragma unroll
                for (int fc = 0; fc < 4; ++fc) {
                    float s = (nz4[fr][e] + ne[fc]) - 2.0f * acc[fr][fc][e];
                    m = fminf(m, s);
                }
                m4[fr][e] = m;
                #pragma unroll
                for (int off = 1; off < 16; off <<= 1)
                    m = fminf(m, __shfl_xor(m, off));
                if (lm == 0)
                    atomicMin(&rowmin[fr * 16 + q * 4 + e], __float_as_uint(m));
            }
        }
        // threshold read (stale rowmin >= finalMin, so capture guarantee holds)
        #pragma unroll
        for (int fr = 0; fr < 4; ++fr) {
            uint4 u = *(const uint4*)&rowmin[fr * 16 + q * 4];
            float thr0 = __uint_as_float(u.x) + MARGIN;
            float thr1 = __uint_as_float(u.y) + MARGIN;
            float thr2 = __uint_as_float(u.z) + MARGIN;
            float thr3 = __uint_as_float(u.w) + MARGIN;
            f32x4 thr = {thr0, thr1, thr2, thr3};
            #pragma unroll
            for (int e = 0; e < 4; ++e) {
                if (m4[fr][e] >= thr[e]) continue;   // fast skip: no candidate in this row-slice
                int row = fr * 16 + q * 4 + e;
                #pragma unroll
                for (int fc = 0; fc < 4; ++fc) {
                    float s = (nz4[fr][e] + ne[fc]) - 2.0f * acc[fr][fc][e];
                    if (s < thr[e]) {
                        int slot = atomicAdd(&cnt[row], 1);
                        if (slot < CAP) candT[slot][row] = codeBase + fc * 16 + lm;
                    }
                }
            }
        }
    }
    __syncthreads();

    // ================= exact rescore (bit-exact R2 semantics, unchanged) ========
    const int r = tid & 63;        // one row per lane
    const int c0 = tid >> 6;       // candidate slot stride-8
    const int grow = rowBase + r;
    const float Anz = znorm[grow];
    const float4* zp4 = (const float4*)(z + ((size_t)grow << 8));

    float bestS = 3.4e38f; int bestK = 0x7fffffff;
    {
        const int n = min(cnt[r], CAP);
        for (int c = c0; c < n; c += 8) {
            int k = candT[c][r];
            const float4* ep4 = (const float4*)(emb + ((size_t)k << 8));
            float s = 0.f;
            #pragma unroll 8
            for (int d4 = 0; d4 < 64; ++d4) {
                float4 a = zp4[d4], b = ep4[d4];
                s = s + a.x * b.x;   // strict mul-then-add, ascending d
                s = s + a.y * b.y;
                s = s + a.z * b.z;
                s = s + a.w * b.w;
            }
            float sc = (Anz + enorm[k]) - 2.0f * s;
            if (sc < bestS || (sc == bestS && k < bestK)) { bestS = sc; bestK = k; }
        }
    }
    if (bestK != 0x7fffffff) atomicMin(&sbits[r], __float_as_uint(bestS));
    if (tid < BM && cnt[tid] > CAP) {          // overflow rows (should be never)
        int o = atomicAdd(&ovCnt, 1);
        if (o < 16) ovList[o] = tid;
    }
    __syncthreads();

    // rare cooperative fallback: full exact scan for overflow rows
    const int nov = min(ovCnt, 16);
    for (int o = 0; o < nov; ++o) {
        const int rr = ovList[o];
        const float Az = znorm[rowBase + rr];
        const float4* zr4 = (const float4*)(z + ((size_t)(rowBase + rr) << 8));
        float bS = 3.4e38f; int bK = 0x7fffffff;
        for (int k = tid; k < K; k += 512) {
            const float4* ep4 = (const float4*)(emb + ((size_t)k << 8));
            float s = 0.f;
            #pragma unroll 8
            for (int d4 = 0; d4 < 64; ++d4) {
                float4 a = zr4[d4], b = ep4[d4];
                s = s + a.x * b.x; s = s + a.y * b.y;
                s = s + a.z * b.z; s = s + a.w * b.w;
            }
            float sc = (Az + enorm[k]) - 2.0f * s;
            if (sc < bS || (sc == bS && k < bK)) { bS = sc; bK = k; }
        }
        atomicMin(&sbits[rr], __float_as_uint(bS));
        __syncthreads();
        if (__float_as_uint(bS) == sbits[rr]) atomicMin(&sidx[rr], bK);
        __syncthreads();
    }

    // stage 2: first-index tie-break among exact-score minima
    if (bestK != 0x7fffffff && __float_as_uint(bestS) == sbits[r])
        atomicMin(&sidx[r], bestK);
    __syncthreads();
    if (tid < BM) idxf[rowBase + tid] = (float)sidx[tid];
}

// -------- kernel 3: gather z_q + loss accumulation --------
__global__ __launch_bounds__(256) void vq_gather(
    const float* __restrict__ z, const float* __restrict__ emb,
    const float* __restrict__ idxf, float* __restrict__ zq,
    float* __restrict__ loss, float scale) {
    const int tid = threadIdx.x;
    const int lane = tid & 63, w = tid >> 6;
    const int rowBase = blockIdx.x * 64;
    float lsum = 0.f;
    for (int t = 0; t < 16; ++t) {
        int gr = rowBase + w * 16 + t;
        int k = (int)idxf[gr];
        float4 e  = ((const float4*)emb)[(size_t)k * 64 + lane];
        float4 zv = ((const float4*)z)[(size_t)gr * 64 + lane];
        ((float4*)zq)[(size_t)gr * 64 + lane] = e;
        float dx = e.x - zv.x, dy = e.y - zv.y, dz = e.z - zv.z, dw = e.w - zv.w;
        lsum = fmaf(dx, dx, lsum); lsum = fmaf(dy, dy, lsum);
        lsum = fmaf(dz, dz, lsum); lsum = fmaf(dw, dw, lsum);
    }
    #pragma unroll
    for (int off = 32; off; off >>= 1) lsum += __shfl_down(lsum, off);
    __shared__ float ps[4];
    if (lane == 0) ps[w] = lsum;
    __syncthreads();
    if (tid == 0) atomicAdd(loss, (ps[0] + ps[1] + ps[2] + ps[3]) * scale);
}

extern "C" void kernel_launch(void* const* d_in, const int* in_sizes, int n_in,
                              void* d_out, int out_size, void* d_ws, size_t ws_size,
                              hipStream_t stream) {
    const float* z   = (const float*)d_in[0];
    const float* emb = (const float*)d_in[1];
    const int N = in_sizes[0] / D;   // 16384
    const int K = in_sizes[1] / D;   // 8192

    float* out  = (float*)d_out;
    float* zq   = out;
    const size_t Z = (size_t)N * D;  // 4,194,304 floats
    float* loss = out + Z;
    float* idxf = loss + 1;

    // scratch in the zq tail region (overwritten by gather at the end):
    char* base = (char*)zq;
    unsigned short* eb = (unsigned short*)base;                          // 4 MB
    unsigned short* zb = (unsigned short*)(base + (size_t)K * D * 2);    // 8 MB
    float* znorm = (float*)(base + (size_t)K * D * 2 + (size_t)N * D * 2);
    float* enorm = znorm + N;

    const int n4z = (N * D) / 4, n4e = (K * D) / 4;
    vq_tobf16 <<<(n4z + 255) / 256, 256, 0, stream>>>(z, zb, n4z);
    vq_tobf16 <<<(n4e + 255) / 256, 256, 0, stream>>>(emb, eb, n4e);
    vq_rownorm<<<(N + 255) / 256, 256, 0, stream>>>(z, znorm, N, loss);
    vq_rownorm<<<(K + 255) / 256, 256, 0, stream>>>(emb, enorm, K, loss);
    vq_argmin_mfma<<<N / BM, 512, 0, stream>>>(z, emb, zb, eb, znorm, enorm, idxf, K);
    vq_gather <<<N / 64, 256, 0, stream>>>(z, emb, idxf, zq, loss,
                                           1.25f / ((float)N * (float)D));
}

// Round 7
// 510.590 us; speedup vs baseline: 1.0021x; 1.0021x over previous
//
#include <hip/hip_runtime.h>
#include <hip/hip_bf16.h>

#define D 256
#define BM 64
#define BN 512      // codes per tile (8 waves x 64)
#define NT 16       // 8192 / BN
#define NIT 128     // NT * 8 kc-chunks
#define CAP 64
#define MARGIN 1.2e-3f

typedef short bf16x8 __attribute__((ext_vector_type(8)));
typedef float f32x4 __attribute__((ext_vector_type(4)));

__device__ inline unsigned short f2bf(float f) {
    __hip_bfloat16 h = __float2bfloat16(f);
    return *reinterpret_cast<unsigned short*>(&h);
}

// -------- kernel 0: fp32 -> bf16 convert (vectorized) --------
__global__ __launch_bounds__(256) void vq_tobf16(const float* __restrict__ in,
                                                 unsigned short* __restrict__ out, int n4) {
    int i = blockIdx.x * 256 + threadIdx.x;
    if (i >= n4) return;
    float4 v = ((const float4*)in)[i];
    ushort4 o;
    o.x = f2bf(v.x); o.y = f2bf(v.y); o.z = f2bf(v.z); o.w = f2bf(v.w);
    ((ushort4*)out)[i] = o;
}

// -------- kernel 1: sequential fp32 row sum-of-squares (XLA elemental order) ----
__global__ __launch_bounds__(256) void vq_rownorm(const float* __restrict__ x,
                                                  float* __restrict__ out,
                                                  int rows, float* loss_zero) {
#pragma clang fp contract(off)
    int r = blockIdx.x * blockDim.x + threadIdx.x;
    if (r == 0 && loss_zero) loss_zero[0] = 0.f;
    if (r >= rows) return;
    const float* p = x + (size_t)r * D;
    float s = 0.f;
    for (int d = 0; d < D; ++d) {
        float v = p[d];
        float pr = v * v;
        s = s + pr;
    }
    out[r] = s;
}

// -------- kernel 2: single-pass MFMA filter (reg-dbuf direct-global B) + rescore
__global__ __launch_bounds__(512, 2) void vq_argmin_mfma(
    const float* __restrict__ z, const float* __restrict__ emb,
    const unsigned short* __restrict__ zb, const unsigned short* __restrict__ eb,
    const float* __restrict__ znorm, const float* __restrict__ enorm,
    float* __restrict__ idxf, int K) {
#pragma clang fp contract(off)
    __shared__ unsigned short zsh[BM][264];   // 33,792 B
    __shared__ unsigned rowmin[BM];
    __shared__ int cnt[BM];
    __shared__ int candT[CAP][BM];            // 16,384 B (slot-major)
    __shared__ unsigned sbits[BM];
    __shared__ int sidx[BM];
    __shared__ int ovList[16];
    __shared__ int ovCnt;

    const int tid = threadIdx.x;
    const int w = tid >> 6;        // wave 0..7
    const int l = tid & 63;
    const int q = l >> 4;          // 0..3
    const int lm = l & 15;
    const int rowBase = blockIdx.x * BM;

    if (tid < BM) {
        rowmin[tid] = 0x7f800000u; cnt[tid] = 0;
        sbits[tid] = 0xffffffffu;  sidx[tid] = 0x7fffffff;
    }
    if (tid == 0) ovCnt = 0;

    // stage z tile (bf16) into padded LDS (R4/R5-verified mapping)
    #pragma unroll
    for (int rc = 0; rc < 4; ++rc) {
        int idx8 = tid + rc * 512;
        int row = idx8 >> 5, c8 = idx8 & 31;
        uint4 v = *(const uint4*)(zb + (((size_t)(rowBase + row)) << 8) + c8 * 8);
        *(uint4*)&zsh[row][c8 * 8] = v;
    }

    f32x4 nz4[4];
    #pragma unroll
    for (int fr = 0; fr < 4; ++fr)
        nz4[fr] = *(const f32x4*)&znorm[rowBase + fr * 16 + q * 4];

    // direct global->reg load of this wave's 4 B-fragments for kc-chunk it2
    auto LOADB = [&](bf16x8* dst, int it2) {
        const int tile2 = it2 >> 3, kc2 = it2 & 7;
        const int cb = tile2 * BN + w * 64;
        const unsigned short* ebw = eb + ((size_t)cb << 8) + kc2 * 32 + q * 8;
        #pragma unroll
        for (int fc = 0; fc < 4; ++fc)
            dst[fc] = *(const bf16x8*)(ebw + (((size_t)(fc * 16 + lm)) << 8));
    };

    __syncthreads();   // zsh + init visible

    bf16x8 bA[4], bB[4];
    LOADB(bA, 0);      // prologue: kc-chunk 0 in flight

    for (int tile = 0; tile < NT; ++tile) {
        const int codeBase = tile * BN + w * 64;
        float ne[4];
        #pragma unroll
        for (int fc = 0; fc < 4; ++fc) ne[fc] = enorm[codeBase + fc * 16 + lm];

        f32x4 acc[4][4];
        #pragma unroll
        for (int a = 0; a < 4; ++a)
            #pragma unroll
            for (int b = 0; b < 4; ++b) acc[a][b] = (f32x4)0.f;

        #pragma unroll
        for (int kc = 0; kc < 8; ++kc) {               // fully unrolled: kc&1 static
            const int it = tile * 8 + kc;
            bf16x8* curB = (kc & 1) ? bB : bA;
            bf16x8* nxtB = (kc & 1) ? bA : bB;
            if (it + 1 < NIT) LOADB(nxtB, it + 1);     // depth-1 reg prefetch

            bf16x8 af[4];
            #pragma unroll
            for (int fr = 0; fr < 4; ++fr)
                af[fr] = *(const bf16x8*)&zsh[fr * 16 + lm][kc * 32 + q * 8];

            __builtin_amdgcn_s_setprio(1);
            #pragma unroll
            for (int fr = 0; fr < 4; ++fr)
                #pragma unroll
                for (int fc = 0; fc < 4; ++fc)
                    acc[fr][fc] = __builtin_amdgcn_mfma_f32_16x16x32_bf16(af[fr], curB[fc], acc[fr][fc], 0, 0, 0);
            __builtin_amdgcn_s_setprio(0);
        }

        // ---- tile epilogue (no barriers): reg-min -> atomicMin -> collect ----
        f32x4 m4[4];
        #pragma unroll
        for (int fr = 0; fr < 4; ++fr) {
            #pragma unroll
            for (int e = 0; e < 4; ++e) {
                float m = 3.4e38f;
                #pragma unroll
                for (int fc = 0; fc < 4; ++fc) {
                    float s = (nz4[fr][e] + ne[fc]) - 2.0f * acc[fr][fc][e];
                    m = fminf(m, s);
                }
                m4[fr][e] = m;
                #pragma unroll
                for (int off = 1; off < 16; off <<= 1)
                    m = fminf(m, __shfl_xor(m, off));
                if (lm == 0)
                    atomicMin(&rowmin[fr * 16 + q * 4 + e], __float_as_uint(m));
            }
        }
        // threshold read (stale rowmin >= finalMin, so capture guarantee holds)
        #pragma unroll
        for (int fr = 0; fr < 4; ++fr) {
            uint4 u = *(const uint4*)&rowmin[fr * 16 + q * 4];
            f32x4 thr = {__uint_as_float(u.x) + MARGIN, __uint_as_float(u.y) + MARGIN,
                         __uint_as_float(u.z) + MARGIN, __uint_as_float(u.w) + MARGIN};
            #pragma unroll
            for (int e = 0; e < 4; ++e) {
                if (m4[fr][e] >= thr[e]) continue;   // fast skip
                int row = fr * 16 + q * 4 + e;
                #pragma unroll
                for (int fc = 0; fc < 4; ++fc) {
                    float s = (nz4[fr][e] + ne[fc]) - 2.0f * acc[fr][fc][e];
                    if (s < thr[e]) {
                        int slot = atomicAdd(&cnt[row], 1);
                        if (slot < CAP) candT[slot][row] = codeBase + fc * 16 + lm;
                    }
                }
            }
        }
    }
    __syncthreads();

    // ================= exact rescore (bit-exact R2 semantics, unchanged) ========
    const int r = tid & 63;        // one row per lane
    const int c0 = tid >> 6;       // candidate slot stride-8
    const int grow = rowBase + r;
    const float Anz = znorm[grow];
    const float4* zp4 = (const float4*)(z + ((size_t)grow << 8));

    float bestS = 3.4e38f; int bestK = 0x7fffffff;
    {
        const int n = min(cnt[r], CAP);
        for (int c = c0; c < n; c += 8) {
            int k = candT[c][r];
            const float4* ep4 = (const float4*)(emb + ((size_t)k << 8));
            float s = 0.f;
            #pragma unroll 8
            for (int d4 = 0; d4 < 64; ++d4) {
                float4 a = zp4[d4], b = ep4[d4];
                s = s + a.x * b.x;   // strict mul-then-add, ascending d
                s = s + a.y * b.y;
                s = s + a.z * b.z;
                s = s + a.w * b.w;
            }
            float sc = (Anz + enorm[k]) - 2.0f * s;
            if (sc < bestS || (sc == bestS && k < bestK)) { bestS = sc; bestK = k; }
        }
    }
    if (bestK != 0x7fffffff) atomicMin(&sbits[r], __float_as_uint(bestS));
    if (tid < BM && cnt[tid] > CAP) {          // overflow rows (should be never)
        int o = atomicAdd(&ovCnt, 1);
        if (o < 16) ovList[o] = tid;
    }
    __syncthreads();

    // rare cooperative fallback: full exact scan for overflow rows
    const int nov = min(ovCnt, 16);
    for (int o = 0; o < nov; ++o) {
        const int rr = ovList[o];
        const float Az = znorm[rowBase + rr];
        const float4* zr4 = (const float4*)(z + ((size_t)(rowBase + rr) << 8));
        float bS = 3.4e38f; int bK = 0x7fffffff;
        for (int k = tid; k < K; k += 512) {
            const float4* ep4 = (const float4*)(emb + ((size_t)k << 8));
            float s = 0.f;
            #pragma unroll 8
            for (int d4 = 0; d4 < 64; ++d4) {
                float4 a = zr4[d4], b = ep4[d4];
                s = s + a.x * b.x; s = s + a.y * b.y;
                s = s + a.z * b.z; s = s + a.w * b.w;
            }
            float sc = (Az + enorm[k]) - 2.0f * s;
            if (sc < bS || (sc == bS && k < bK)) { bS = sc; bK = k; }
        }
        atomicMin(&sbits[rr], __float_as_uint(bS));
        __syncthreads();
        if (__float_as_uint(bS) == sbits[rr]) atomicMin(&sidx[rr], bK);
        __syncthreads();
    }

    // stage 2: first-index tie-break among exact-score minima
    if (bestK != 0x7fffffff && __float_as_uint(bestS) == sbits[r])
        atomicMin(&sidx[r], bestK);
    __syncthreads();
    if (tid < BM) idxf[rowBase + tid] = (float)sidx[tid];
}

// -------- kernel 3: gather z_q + loss accumulation --------
__global__ __launch_bounds__(256) void vq_gather(
    const float* __restrict__ z, const float* __restrict__ emb,
    const float* __restrict__ idxf, float* __restrict__ zq,
    float* __restrict__ loss, float scale) {
    const int tid = threadIdx.x;
    const int lane = tid & 63, w = tid >> 6;
    const int rowBase = blockIdx.x * 64;
    float lsum = 0.f;
    for (int t = 0; t < 16; ++t) {
        int gr = rowBase + w * 16 + t;
        int k = (int)idxf[gr];
        float4 e  = ((const float4*)emb)[(size_t)k * 64 + lane];
        float4 zv = ((const float4*)z)[(size_t)gr * 64 + lane];
        ((float4*)zq)[(size_t)gr * 64 + lane] = e;
        float dx = e.x - zv.x, dy = e.y - zv.y, dz = e.z - zv.z, dw = e.w - zv.w;
        lsum = fmaf(dx, dx, lsum); lsum = fmaf(dy, dy, lsum);
        lsum = fmaf(dz, dz, lsum); lsum = fmaf(dw, dw, lsum);
    }
    #pragma unroll
    for (int off = 32; off; off >>= 1) lsum += __shfl_down(lsum, off);
    __shared__ float ps[4];
    if (lane == 0) ps[w] = lsum;
    __syncthreads();
    if (tid == 0) atomicAdd(loss, (ps[0] + ps[1] + ps[2] + ps[3]) * scale);
}

extern "C" void kernel_launch(void* const* d_in, const int* in_sizes, int n_in,
                              void* d_out, int out_size, void* d_ws, size_t ws_size,
                              hipStream_t stream) {
    const float* z   = (const float*)d_in[0];
    const float* emb = (const float*)d_in[1];
    const int N = in_sizes[0] / D;   // 16384
    const int K = in_sizes[1] / D;   // 8192

    float* out  = (float*)d_out;
    float* zq   = out;
    const size_t Z = (size_t)N * D;  // 4,194,304 floats
    float* loss = out + Z;
    float* idxf = loss + 1;

    // scratch in the zq tail region (overwritten by gather at the end):
    char* base = (char*)zq;
    unsigned short* eb = (unsigned short*)base;                          // 4 MB
    unsigned short* zb = (unsigned short*)(base + (size_t)K * D * 2);    // 8 MB
    float* znorm = (float*)(base + (size_t)K * D * 2 + (size_t)N * D * 2);
    float* enorm = znorm + N;

    const int n4z = (N * D) / 4, n4e = (K * D) / 4;
    vq_tobf16 <<<(n4z + 255) / 256, 256, 0, stream>>>(z, zb, n4z);
    vq_tobf16 <<<(n4e + 255) / 256, 256, 0, stream>>>(emb, eb, n4e);
    vq_rownorm<<<(N + 255) / 256, 256, 0, stream>>>(z, znorm, N, loss);
    vq_rownorm<<<(K + 255) / 256, 256, 0, stream>>>(emb, enorm, K, loss);
    vq_argmin_mfma<<<N / BM, 512, 0, stream>>>(z, emb, zb, eb, znorm, enorm, idxf, K);
    vq_gather <<<N / 64, 256, 0, stream>>>(z, emb, idxf, zq, loss,
                                           1.25f / ((float)N * (float)D));
}